// Round 1
// baseline (398.834 us; speedup 1.0000x reference)
//
#include <hip/hip_runtime.h>
#include <hip/hip_bf16.h>

#define RR 100
#define MID 256
#define NN 384

// ---------------- Factor nets ----------------
// Two-layer: out[i,r] = b2[r] + sum_m sin(1.5*(x[i]*W1[m]+b1[m])) * W2[r,m]
__global__ __launch_bounds__(256) void factor2(
    const float* __restrict__ x, const float* __restrict__ W1,
    const float* __restrict__ b1, const float* __restrict__ W2,
    const float* __restrict__ b2, float* __restrict__ out) {
  __shared__ float h[MID];
  const int i = blockIdx.x;
  const int t = threadIdx.x;
  const float xv = x[i];
  h[t] = sinf(1.5f * (xv * W1[t] + b1[t]));
  __syncthreads();
  if (t < RR) {
    float acc = b2[t];
    const float* __restrict__ w = &W2[t * MID];
#pragma unroll 8
    for (int m = 0; m < MID; ++m) acc += h[m] * w[m];
    out[i * RR + t] = acc;
  }
}

// Three-layer (C factor)
__global__ __launch_bounds__(256) void factor3(
    const float* __restrict__ x, const float* __restrict__ W1,
    const float* __restrict__ b1, const float* __restrict__ W2,
    const float* __restrict__ b2, const float* __restrict__ W3,
    const float* __restrict__ b3, float* __restrict__ out) {
  __shared__ float h1[MID];
  __shared__ float h2[MID];
  const int i = blockIdx.x;
  const int t = threadIdx.x;
  const float xv = x[i];
  h1[t] = sinf(1.5f * (xv * W1[t] + b1[t]));
  __syncthreads();
  {
    float acc = b2[t];
    const float* __restrict__ w = &W2[t * MID];
#pragma unroll 8
    for (int m = 0; m < MID; ++m) acc += h1[m] * w[m];
    h2[t] = sinf(1.5f * acc);
  }
  __syncthreads();
  if (t < RR) {
    float acc = b3[t];
    const float* __restrict__ w = &W3[t * MID];
#pragma unroll 8
    for (int m = 0; m < MID; ++m) acc += h2[m] * w[m];
    out[i * RR + t] = acc;
  }
}

// ---------------- CP contraction ----------------
// out[i,j,k] = sum_r A[i,r]*B[j,r]*C[k,r]
// Block tile: 16 (i) x 16 (j) x 64 (k). 256 threads.
// Thread: kx = tid&63 (k within tile), q = tid>>6 (j quarter).
// Each thread accumulates acc[16][4] over all r: i = i0+a, j = j0+q*4+b, k = k0+kx.
// LDS: At[r][i] / Bt[r][j] broadcast reads (whole wave same addr, free);
//      Ct[r][k] stride-1 reads (2 lanes/bank, free).
__global__ __launch_bounds__(256) void cp_contract(
    const float* __restrict__ A, const float* __restrict__ B,
    const float* __restrict__ C, float* __restrict__ out) {
  __shared__ float At[RR][16];
  __shared__ float Bt[RR][16];
  __shared__ float Ct[RR][64];
  const int i0 = blockIdx.z * 16;
  const int j0 = blockIdx.y * 16;
  const int k0 = blockIdx.x * 64;
  const int tid = threadIdx.x;

  // Stage tiles. LDS writes are lane-contiguous (conflict-free); global reads
  // are strided but A/B/C are ~150 KB each -> L2-resident.
  for (int idx = tid; idx < 16 * RR; idx += 256) {
    const int ii = idx & 15;
    const int r = idx >> 4;
    At[r][ii] = A[(i0 + ii) * RR + r];
    Bt[r][ii] = B[(j0 + ii) * RR + r];
  }
  for (int idx = tid; idx < 64 * RR; idx += 256) {
    const int kk = idx & 63;
    const int r = idx >> 6;
    Ct[r][kk] = C[(k0 + kk) * RR + r];
  }
  __syncthreads();

  const int kx = tid & 63;
  const int q = tid >> 6;

  float acc[16][4];
#pragma unroll
  for (int a = 0; a < 16; ++a)
#pragma unroll
    for (int b = 0; b < 4; ++b) acc[a][b] = 0.0f;

  for (int r = 0; r < RR; ++r) {
    const float c = Ct[r][kx];
    const float4 bv = *(const float4*)&Bt[r][q * 4];
    const float p0 = bv.x * c;
    const float p1 = bv.y * c;
    const float p2 = bv.z * c;
    const float p3 = bv.w * c;
#pragma unroll
    for (int a4 = 0; a4 < 4; ++a4) {
      const float4 av = *(const float4*)&At[r][a4 * 4];
      acc[a4 * 4 + 0][0] += av.x * p0;
      acc[a4 * 4 + 0][1] += av.x * p1;
      acc[a4 * 4 + 0][2] += av.x * p2;
      acc[a4 * 4 + 0][3] += av.x * p3;
      acc[a4 * 4 + 1][0] += av.y * p0;
      acc[a4 * 4 + 1][1] += av.y * p1;
      acc[a4 * 4 + 1][2] += av.y * p2;
      acc[a4 * 4 + 1][3] += av.y * p3;
      acc[a4 * 4 + 2][0] += av.z * p0;
      acc[a4 * 4 + 2][1] += av.z * p1;
      acc[a4 * 4 + 2][2] += av.z * p2;
      acc[a4 * 4 + 2][3] += av.z * p3;
      acc[a4 * 4 + 3][0] += av.w * p0;
      acc[a4 * 4 + 3][1] += av.w * p1;
      acc[a4 * 4 + 3][2] += av.w * p2;
      acc[a4 * 4 + 3][3] += av.w * p3;
    }
  }

  // Store: lanes within a wave have consecutive kx -> 256B coalesced dword stores.
  const int jb = j0 + q * 4;
#pragma unroll
  for (int a = 0; a < 16; ++a) {
    const int row = (i0 + a) * NN;
#pragma unroll
    for (int b = 0; b < 4; ++b) {
      out[(row + jb + b) * NN + k0 + kx] = acc[a][b];
    }
  }
}

extern "C" void kernel_launch(void* const* d_in, const int* in_sizes, int n_in,
                              void* d_out, int out_size, void* d_ws, size_t ws_size,
                              hipStream_t stream) {
  const float* A_input = (const float*)d_in[0];
  const float* B_input = (const float*)d_in[1];
  const float* C_input = (const float*)d_in[2];
  const float* A_W1 = (const float*)d_in[3];
  const float* A_b1 = (const float*)d_in[4];
  const float* A_W2 = (const float*)d_in[5];
  const float* A_b2 = (const float*)d_in[6];
  const float* B_W1 = (const float*)d_in[7];
  const float* B_b1 = (const float*)d_in[8];
  const float* B_W2 = (const float*)d_in[9];
  const float* B_b2 = (const float*)d_in[10];
  const float* C_W1 = (const float*)d_in[11];
  const float* C_b1 = (const float*)d_in[12];
  const float* C_W2 = (const float*)d_in[13];
  const float* C_b2 = (const float*)d_in[14];
  const float* C_W3 = (const float*)d_in[15];
  const float* C_b3 = (const float*)d_in[16];

  float* Af = (float*)d_ws;                 // 384*100
  float* Bf = Af + NN * RR;                 // 384*100
  float* Cf = Bf + NN * RR;                 // 384*100

  factor2<<<NN, 256, 0, stream>>>(A_input, A_W1, A_b1, A_W2, A_b2, Af);
  factor2<<<NN, 256, 0, stream>>>(B_input, B_W1, B_b1, B_W2, B_b2, Bf);
  factor3<<<NN, 256, 0, stream>>>(C_input, C_W1, C_b1, C_W2, C_b2, C_W3, C_b3, Cf);

  dim3 grid(NN / 64, NN / 16, NN / 16);  // k, j, i
  cp_contract<<<grid, 256, 0, stream>>>(Af, Bf, Cf, (float*)d_out);
}

// Round 2
// 298.898 us; speedup vs baseline: 1.3343x; 1.3343x over previous
//
#include <hip/hip_runtime.h>
#include <hip/hip_bf16.h>

#define RR 100
#define MID 256
#define NN 384
#define KP 128   // rank padded to 128 (zeros in r=100..127)

typedef __attribute__((ext_vector_type(8))) __bf16 bf16x8;
typedef __attribute__((ext_vector_type(4))) float floatx4;
typedef unsigned short ushort_t;

// Swizzled LDS offset (elements) for row-major [128][KP] bf16 tiles stored as
// 16 chunks of 8 bf16 per row; chunk index XOR'd with (row&15) so that
// MFMA fragment reads (16 rows x same chunk) spread across all 32 banks.
#define SW(row, ch) ((((row) << 7)) + ((((ch) ^ ((row) & 15))) << 3))

__device__ __forceinline__ ushort_t f2bf(float f) {
  __hip_bfloat16 h = __float2bfloat16(f);
  return __builtin_bit_cast(ushort_t, h);
}

// ---------------- Factor nets (all three in one launch) ----------------
// blockIdx.x = row i (0..383), blockIdx.y = net (0=A, 1=B, 2=C).
// A,B written as fp32 [384][128] (pad zeros); C written as bf16 [384][128].
__global__ __launch_bounds__(256) void factors_kernel(
    const float* __restrict__ xA, const float* __restrict__ xB,
    const float* __restrict__ xC,
    const float* __restrict__ AW1, const float* __restrict__ Ab1,
    const float* __restrict__ AW2, const float* __restrict__ Ab2,
    const float* __restrict__ BW1, const float* __restrict__ Bb1,
    const float* __restrict__ BW2, const float* __restrict__ Bb2,
    const float* __restrict__ CW1, const float* __restrict__ Cb1,
    const float* __restrict__ CW2, const float* __restrict__ Cb2,
    const float* __restrict__ CW3, const float* __restrict__ Cb3,
    float* __restrict__ Af, float* __restrict__ Bf,
    ushort_t* __restrict__ Cbf) {
  __shared__ float h[MID];
  __shared__ float h2[MID];
  const int i = blockIdx.x;
  const int net = blockIdx.y;
  const int t = threadIdx.x;

  const float* x  = (net == 0) ? xA  : (net == 1) ? xB  : xC;
  const float* W1 = (net == 0) ? AW1 : (net == 1) ? BW1 : CW1;
  const float* b1 = (net == 0) ? Ab1 : (net == 1) ? Bb1 : Cb1;

  const float xv = x[i];
  h[t] = sinf(1.5f * (xv * W1[t] + b1[t]));
  __syncthreads();

  const float* hlast = h;
  if (net == 2) {  // block-uniform branch
    float acc = Cb2[t];
    const float* __restrict__ w = &CW2[t * MID];
#pragma unroll 8
    for (int m = 0; m < MID; ++m) acc += h[m] * w[m];
    h2[t] = sinf(1.5f * acc);
    __syncthreads();
    hlast = h2;
  }

  const float* W2 = (net == 0) ? AW2 : (net == 1) ? BW2 : CW3;
  const float* b2 = (net == 0) ? Ab2 : (net == 1) ? Bb2 : Cb3;

  if (t < KP) {
    float v = 0.0f;
    if (t < RR) {
      float acc = b2[t];
      const float* __restrict__ w = &W2[t * MID];
#pragma unroll 8
      for (int m = 0; m < MID; ++m) acc += hlast[m] * w[m];
      v = acc;
    }
    if (net == 0)      Af[i * KP + t] = v;
    else if (net == 1) Bf[i * KP + t] = v;
    else               Cbf[i * KP + t] = f2bf(v);
  }
}

// ---------------- CP contraction via bf16 MFMA ----------------
// Per block (i fixed): out[i, j0:j0+128, k0:k0+128] = W @ C^T, where
// W[jx][r] = A[i,r]*B[j0+jx,r] (fp32 product, one bf16 rounding) and
// C[kx][r] bf16. K padded to 128 with zeros. 4 waves, each a 64x64 subtile
// of 16x16x32 MFMA fragments.
__global__ __launch_bounds__(256, 2) void cp_mfma(
    const float* __restrict__ Af, const float* __restrict__ Bf,
    const ushort_t* __restrict__ Cbf, float* __restrict__ out) {
  __shared__ ushort_t Wt[128 * KP];  // 32 KB
  __shared__ ushort_t Ct[128 * KP];  // 32 KB

  const int i  = blockIdx.z;
  const int j0 = blockIdx.y * 128;
  const int k0 = blockIdx.x * 128;
  const int t  = threadIdx.x;

  // ---- stage C tile: plain bf16 copy into swizzled LDS (16B chunks) ----
#pragma unroll
  for (int it = 0; it < 8; ++it) {
    const int idx = t + 256 * it;
    const int row = idx >> 4;
    const int ch  = idx & 15;
    *(uint4*)&Ct[SW(row, ch)] =
        *(const uint4*)&Cbf[(size_t)(k0 + row) * KP + ch * 8];
  }

  // ---- compute W tile: 2 threads per row, 64 r's each ----
  {
    const int jx = t >> 1;
    const int hh = t & 1;
    const float* __restrict__ arow = Af + (size_t)i * KP + hh * 64;
    const float* __restrict__ brow = Bf + (size_t)(j0 + jx) * KP + hh * 64;
#pragma unroll
    for (int c = 0; c < 8; ++c) {
      const float4 a0 = *(const float4*)(arow + c * 8);
      const float4 a1 = *(const float4*)(arow + c * 8 + 4);
      const float4 b0 = *(const float4*)(brow + c * 8);
      const float4 b1 = *(const float4*)(brow + c * 8 + 4);
      uint4 wv;
      wv.x = (unsigned)f2bf(a0.x * b0.x) | ((unsigned)f2bf(a0.y * b0.y) << 16);
      wv.y = (unsigned)f2bf(a0.z * b0.z) | ((unsigned)f2bf(a0.w * b0.w) << 16);
      wv.z = (unsigned)f2bf(a1.x * b1.x) | ((unsigned)f2bf(a1.y * b1.y) << 16);
      wv.w = (unsigned)f2bf(a1.z * b1.z) | ((unsigned)f2bf(a1.w * b1.w) << 16);
      *(uint4*)&Wt[SW(jx, hh * 8 + c)] = wv;
    }
  }
  __syncthreads();

  // ---- MFMA main loop ----
  const int lane = t & 63;
  const int w    = t >> 6;
  const int wj   = (w & 1) * 64;
  const int wk   = (w >> 1) * 64;
  const int m16  = lane & 15;
  const int g    = lane >> 4;

  floatx4 acc[4][4];
#pragma unroll
  for (int jf = 0; jf < 4; ++jf)
#pragma unroll
    for (int kf = 0; kf < 4; ++kf) acc[jf][kf] = (floatx4)0.0f;

#pragma unroll
  for (int ks = 0; ks < 4; ++ks) {
    bf16x8 af[4], bfr[4];
#pragma unroll
    for (int f = 0; f < 4; ++f) {
      af[f]  = *(const bf16x8*)&Wt[SW(wj + f * 16 + m16, ks * 4 + g)];
      bfr[f] = *(const bf16x8*)&Ct[SW(wk + f * 16 + m16, ks * 4 + g)];
    }
#pragma unroll
    for (int jf = 0; jf < 4; ++jf)
#pragma unroll
      for (int kf = 0; kf < 4; ++kf)
        acc[jf][kf] = __builtin_amdgcn_mfma_f32_16x16x32_bf16(
            af[jf], bfr[kf], acc[jf][kf], 0, 0, 0);
  }

  // ---- epilogue: D layout col=lane&15 (k), row=g*4+reg (j) ----
  const size_t ibase = (size_t)i * NN * NN;
#pragma unroll
  for (int jf = 0; jf < 4; ++jf) {
    const int j = j0 + wj + jf * 16 + g * 4;
#pragma unroll
    for (int kf = 0; kf < 4; ++kf) {
      const int k = k0 + wk + kf * 16 + m16;
#pragma unroll
      for (int r = 0; r < 4; ++r) {
        out[ibase + (size_t)(j + r) * NN + k] = acc[jf][kf][r];
      }
    }
  }
}

extern "C" void kernel_launch(void* const* d_in, const int* in_sizes, int n_in,
                              void* d_out, int out_size, void* d_ws, size_t ws_size,
                              hipStream_t stream) {
  const float* A_input = (const float*)d_in[0];
  const float* B_input = (const float*)d_in[1];
  const float* C_input = (const float*)d_in[2];
  const float* A_W1 = (const float*)d_in[3];
  const float* A_b1 = (const float*)d_in[4];
  const float* A_W2 = (const float*)d_in[5];
  const float* A_b2 = (const float*)d_in[6];
  const float* B_W1 = (const float*)d_in[7];
  const float* B_b1 = (const float*)d_in[8];
  const float* B_W2 = (const float*)d_in[9];
  const float* B_b2 = (const float*)d_in[10];
  const float* C_W1 = (const float*)d_in[11];
  const float* C_b1 = (const float*)d_in[12];
  const float* C_W2 = (const float*)d_in[13];
  const float* C_b2 = (const float*)d_in[14];
  const float* C_W3 = (const float*)d_in[15];
  const float* C_b3 = (const float*)d_in[16];

  // ws layout: Af fp32 [384][128] | Bf fp32 [384][128] | Cbf bf16 [384][128]
  float* Af = (float*)d_ws;                       // 196,608 B
  float* Bf = Af + NN * KP;                       // 196,608 B
  ushort_t* Cbf = (ushort_t*)(Bf + NN * KP);      //  98,304 B  (total 480 KB)

  dim3 fgrid(NN, 3);
  factors_kernel<<<fgrid, 256, 0, stream>>>(
      A_input, B_input, C_input,
      A_W1, A_b1, A_W2, A_b2,
      B_W1, B_b1, B_W2, B_b2,
      C_W1, C_b1, C_W2, C_b2, C_W3, C_b3,
      Af, Bf, Cbf);

  dim3 grid(NN / 128, NN / 128, NN);  // (k-tiles, j-tiles, i)
  cp_mfma<<<grid, 256, 0, stream>>>(Af, Bf, Cbf, (float*)d_out);
}